// Round 3
// baseline (195.263 us; speedup 1.0000x reference)
//
#include <hip/hip_runtime.h>

#define B_ 32
#define C_ 512
#define HW_ 4096
#define N_ 80
#define HSPLIT 4

typedef __bf16 bf16x8 __attribute__((ext_vector_type(8)));
typedef __bf16 bf16x4 __attribute__((ext_vector_type(4)));
typedef float f32x4 __attribute__((ext_vector_type(4)));
typedef unsigned short u16x8 __attribute__((ext_vector_type(8)));

__device__ __forceinline__ void gload_lds16(const void* g, void* l) {
  __builtin_amdgcn_global_load_lds((const __attribute__((address_space(1))) void*)g,
                                   (__attribute__((address_space(3))) void*)l, 16, 0, 0);
}

// ---------------------------------------------------------------------------
// K0: one-time W f32 -> bf16 (80x512)
// ---------------------------------------------------------------------------
__global__ __launch_bounds__(256) void k0_wconv(const float* __restrict__ W,
                                                __bf16* __restrict__ Wbf) {
  const int i = blockIdx.x * 256 + threadIdx.x;
  if (i < N_ * C_) Wbf[i] = (__bf16)W[i];
}

// ---------------------------------------------------------------------------
// K1: logits[b][n][h] (bf16) = sum_c feats[b][c][h] * W[n][c]
// LDS-staged: tile[32 c][128 h] f32 via global_load_lds_dwordx4 (coalesced),
// A-frags transposed out of LDS (ds_read_b32, 4-way conflict acceptable),
// B = Wbf rows (direct u16x8). Block: 4 waves; wave owns [32 h][80 n].
// Grid (HW/128, B). 16 KB LDS, 4 blocks/CU.
// ---------------------------------------------------------------------------
__global__ __launch_bounds__(256, 4) void k1_logits(const float* __restrict__ feats,
                                                    const __bf16* __restrict__ Wbf,
                                                    __bf16* __restrict__ logits) {
  __shared__ float tile[32][128];  // 16 KB
  const int tid = threadIdx.x;
  const int lane = tid & 63, wave = tid >> 6;
  const int quad = lane >> 4, l16 = lane & 15;
  const int b = blockIdx.y;
  const int htile0 = blockIdx.x * 128;
  const float* fb = feats + (size_t)b * (C_ * HW_);

  const f32x4 zero = {0.f, 0.f, 0.f, 0.f};
  f32x4 acc[2][5];
#pragma unroll
  for (int hf = 0; hf < 2; ++hf)
#pragma unroll
    for (int nf = 0; nf < 5; ++nf) acc[hf][nf] = zero;

  // staging map: float4 index f = j*256 + tid -> row f>>5 (c), col4 f&31 (h/4)
  // LDS byte f*16 = j*4096 + wave*1024 + lane*16  (linear, matches gload_lds)
  const int scol = (tid & 31) * 4;       // h offset within tile
  const int srow = tid >> 5;             // base c row (rows srow + 8j)

  for (int c0 = 0; c0 < C_; c0 += 32) {
#pragma unroll
    for (int j = 0; j < 4; ++j) {
      const float* gp = fb + (size_t)(c0 + srow + j * 8) * HW_ + htile0 + scol;
      char* lp = (char*)(&tile[0][0]) + j * 4096 + wave * 1024;
      gload_lds16(gp, lp);
    }
    __syncthreads();  // drains vmcnt before barrier

    bf16x8 afr[2];
#pragma unroll
    for (int hf = 0; hf < 2; ++hf) {
      const int col = wave * 32 + hf * 16 + l16;
#pragma unroll
      for (int i = 0; i < 8; ++i) afr[hf][i] = (__bf16)tile[quad * 8 + i][col];
    }
#pragma unroll
    for (int nf = 0; nf < 5; ++nf) {
      const u16x8 bv =
          *(const u16x8*)(Wbf + (unsigned)(nf * 16 + l16) * C_ + (unsigned)(c0 + quad * 8));
      const bf16x8 bfr = __builtin_bit_cast(bf16x8, bv);
#pragma unroll
      for (int hf = 0; hf < 2; ++hf)
        acc[hf][nf] =
            __builtin_amdgcn_mfma_f32_16x16x32_bf16(afr[hf], bfr, acc[hf][nf], 0, 0, 0);
    }
    __syncthreads();  // protect tile reuse
  }

  // D: row(h) = quad*4 + j, col(n) = l16 -> 4 consecutive h per lane = 8B store
#pragma unroll
  for (int nf = 0; nf < 5; ++nf) {
    const int n = nf * 16 + l16;
#pragma unroll
    for (int hf = 0; hf < 2; ++hf) {
      const int h = htile0 + wave * 32 + hf * 16 + quad * 4;
      bf16x4 pk;
#pragma unroll
      for (int j = 0; j < 4; ++j) pk[j] = (__bf16)acc[hf][nf][j];
      *(bf16x4*)(logits + (size_t)(b * N_ + n) * HW_ + h) = pk;
    }
  }
}

// ---------------------------------------------------------------------------
// K2: in-place row softmax over h. One block per (b,n) row; 256 thr x 16 elems.
// ---------------------------------------------------------------------------
__global__ __launch_bounds__(256) void k2_softmax(__bf16* __restrict__ att) {
  const int tid = threadIdx.x;
  const int lane = tid & 63, wave = tid >> 6;
  __bf16* rp = att + (size_t)blockIdx.x * HW_ + tid * 16;
  const bf16x8 v0 = *(const bf16x8*)(rp);
  const bf16x8 v1 = *(const bf16x8*)(rp + 8);
  float x[16];
#pragma unroll
  for (int i = 0; i < 8; ++i) { x[i] = (float)v0[i]; x[i + 8] = (float)v1[i]; }

  float m = x[0];
#pragma unroll
  for (int i = 1; i < 16; ++i) m = fmaxf(m, x[i]);
#pragma unroll
  for (int off = 32; off >= 1; off >>= 1) m = fmaxf(m, __shfl_xor(m, off));

  __shared__ float red[4];
  if (lane == 0) red[wave] = m;
  __syncthreads();
  m = fmaxf(fmaxf(red[0], red[1]), fmaxf(red[2], red[3]));

  float e[16];
  float s = 0.f;
#pragma unroll
  for (int i = 0; i < 16; ++i) { e[i] = __expf(x[i] - m); s += e[i]; }
#pragma unroll
  for (int off = 32; off >= 1; off >>= 1) s += __shfl_xor(s, off);
  __syncthreads();
  if (lane == 0) red[wave] = s;
  __syncthreads();
  s = red[0] + red[1] + red[2] + red[3];
  const float r = 1.0f / s;

  bf16x8 o0, o1;
#pragma unroll
  for (int i = 0; i < 8; ++i) {
    o0[i] = (__bf16)(e[i] * r);
    o1[i] = (__bf16)(e[i + 8] * r);
  }
  *(bf16x8*)(rp) = o0;
  *(bf16x8*)(rp + 8) = o1;
}

// ---------------------------------------------------------------------------
// K3: partial[hz][b][n][c] = sum_{h in slice hz} att[b][n][h] * feats[b][c][h]
// h split HSPLIT ways -> grid (C/64, B, HSPLIT) = 1024 blocks = 4 blocks/CU.
// A = feats rows (float4 pairs), B = att rows (u16x8). f32 partials to ws.
// ---------------------------------------------------------------------------
__global__ __launch_bounds__(256, 4) void k3_pool(const float* __restrict__ feats,
                                                  const __bf16* __restrict__ att,
                                                  float* __restrict__ part) {
  const int tid = threadIdx.x;
  const int lane = tid & 63, wave = tid >> 6;
  const int quad = lane >> 4, l16 = lane & 15;
  const int b = blockIdx.y;
  const int hz = blockIdx.z;
  const int c0 = blockIdx.x * 64 + wave * 16;
  const float* fb = feats + (size_t)b * (C_ * HW_);
  const __bf16* ab = att + (size_t)b * N_ * HW_;
  const unsigned arow = (unsigned)(c0 + l16) * HW_;
  const int hbeg = hz * (HW_ / HSPLIT);
  const int hend = hbeg + (HW_ / HSPLIT);

  const f32x4 zero = {0.f, 0.f, 0.f, 0.f};
  f32x4 acc[5];
#pragma unroll
  for (int nf = 0; nf < 5; ++nf) acc[nf] = zero;

  for (int h0 = hbeg; h0 < hend; h0 += 32) {
    const unsigned hk = (unsigned)(h0 + quad * 8);
    const float4 a0 = *(const float4*)(fb + arow + hk);
    const float4 a1 = *(const float4*)(fb + arow + hk + 4);
    bf16x8 af;
    af[0] = (__bf16)a0.x; af[1] = (__bf16)a0.y; af[2] = (__bf16)a0.z; af[3] = (__bf16)a0.w;
    af[4] = (__bf16)a1.x; af[5] = (__bf16)a1.y; af[6] = (__bf16)a1.z; af[7] = (__bf16)a1.w;
#pragma unroll
    for (int nf = 0; nf < 5; ++nf) {
      const u16x8 bv = *(const u16x8*)(ab + (unsigned)(nf * 16 + l16) * HW_ + hk);
      const bf16x8 bfr = __builtin_bit_cast(bf16x8, bv);
      acc[nf] = __builtin_amdgcn_mfma_f32_16x16x32_bf16(af, bfr, acc[nf], 0, 0, 0);
    }
  }
  float* pb = part + (size_t)hz * (B_ * N_ * C_);
#pragma unroll
  for (int nf = 0; nf < 5; ++nf) {
    const int n = nf * 16 + l16;
    float4 v;
    v.x = acc[nf][0]; v.y = acc[nf][1]; v.z = acc[nf][2]; v.w = acc[nf][3];
    *(float4*)(pb + (size_t)(b * N_ + n) * C_ + c0 + quad * 4) = v;
  }
}

// ---------------------------------------------------------------------------
// K4: out = sum_hz partial[hz]  (float4 granularity)
// ---------------------------------------------------------------------------
__global__ __launch_bounds__(256) void k4_reduce(const float* __restrict__ part,
                                                 float* __restrict__ out) {
  const size_t i = ((size_t)blockIdx.x * 256 + threadIdx.x) * 4;
  if (i >= (size_t)B_ * N_ * C_) return;
  float4 s = *(const float4*)(part + i);
#pragma unroll
  for (int hz = 1; hz < HSPLIT; ++hz) {
    const float4 v = *(const float4*)(part + (size_t)hz * (B_ * N_ * C_) + i);
    s.x += v.x; s.y += v.y; s.z += v.z; s.w += v.w;
  }
  *(float4*)(out + i) = s;
}

extern "C" void kernel_launch(void* const* d_in, const int* in_sizes, int n_in,
                              void* d_out, int out_size, void* d_ws, size_t ws_size,
                              hipStream_t stream) {
  (void)in_sizes; (void)n_in; (void)out_size; (void)ws_size;
  const float* feats = (const float*)d_in[0];
  const float* Wm = (const float*)d_in[1];
  float* out = (float*)d_out;

  __bf16* att = (__bf16*)d_ws;                          // 21 MB
  __bf16* Wbf = att + (size_t)B_ * N_ * HW_;            // 80 KB
  float* part = (float*)(Wbf + N_ * C_);                // 4 x 5.24 MB (16B-aligned)

  hipLaunchKernelGGL(k0_wconv, dim3((N_ * C_ + 255) / 256), dim3(256), 0, stream, Wm, Wbf);
  hipLaunchKernelGGL(k1_logits, dim3(HW_ / 128, B_), dim3(256), 0, stream, feats, Wbf, att);
  hipLaunchKernelGGL(k2_softmax, dim3(B_ * N_), dim3(256), 0, stream, att);
  hipLaunchKernelGGL(k3_pool, dim3(C_ / 64, B_, HSPLIT), dim3(256), 0, stream, feats, att, part);
  const int n4 = (B_ * N_ * C_) / 4;
  hipLaunchKernelGGL(k4_reduce, dim3((n4 + 255) / 256), dim3(256), 0, stream, part, out);
}